// Round 21
// baseline (624.502 us; speedup 1.0000x reference)
//
#include <hip/hip_runtime.h>

#define NC   50000
#define NE   500000
#define NEP  (NE + 64)
#define DIN  313
#define DNE  580
#define KPC  320          // padded K for child GEMM (10*32)
#define KB   96           // padded K for ef GEMM (3*32)
#define NB_SCAN 196       // ceil(NC/256)

typedef __attribute__((ext_vector_type(8))) short bf16x8;
typedef __attribute__((ext_vector_type(4))) float f32x4;

static __device__ __forceinline__ unsigned short f2bf(float f) {
    unsigned u = __float_as_uint(f);
    unsigned r = (u + 0x7fff + ((u >> 16) & 1)) >> 16;   // RNE
    return (unsigned short)r;
}
static __device__ __forceinline__ float bf2f(unsigned short u) {
    return __uint_as_float(((unsigned)u) << 16);
}
static __device__ __forceinline__ void gload_lds16(const unsigned short* g, unsigned short* l) {
    __builtin_amdgcn_global_load_lds(
        (const __attribute__((address_space(1))) unsigned int*)(g),
        (__attribute__((address_space(3))) unsigned int*)(l), 16, 0, 0);
}

// ---------------- W prep: bf16 transposed, K-chunk XOR-permuted for swizzled gload_lds ----
__global__ __launch_bounds__(256) void prep_w_kernel(
    const float* __restrict__ W0, const float* __restrict__ W1,
    const float* __restrict__ Wc,
    unsigned short* __restrict__ Wpt, unsigned short* __restrict__ Wbt,
    unsigned short* __restrict__ Wct)
{
    int b = blockIdx.x;
    if (b < 1024) {                      // Wpt [layer][n2<512][k<256]
        int layer = b >> 9, n2 = b & 511;
        const float* W = layer ? W1 : W0;
        unsigned short* dst = Wpt + (size_t)layer * 512 * 256 + (size_t)n2 * 256;
        int t = threadIdx.x;
        int ch = t >> 5, s = (t >> 3) & 3, j = t & 7;
        int gk = ch * 32 + ((s ^ (n2 & 3)) * 8) + j;
        float v = (n2 < 256) ? W[(size_t)gk * 256 + n2] : W[(size_t)(256 + gk) * 256 + (n2 - 256)];
        dst[t] = f2bf(v);
    } else if (b < 1536) {               // Wbt [layer][n<256][k<96] XOR-permuted
        int idx = b - 1024;
        int layer = idx >> 8, n = idx & 255;
        const float* W = layer ? W1 : W0;
        unsigned short* dst = Wbt + (size_t)layer * 256 * KB + (size_t)n * KB;
        int t = threadIdx.x;
        if (t < KB) {
            int ch = t >> 5, s = (t >> 3) & 3, j = t & 7;
            int gk = ch * 32 + ((s ^ (n & 3)) * 8) + j;
            float v = (512 + gk < DNE) ? W[(size_t)(512 + gk) * 256 + n] : 0.0f;
            dst[t] = f2bf(v);
        }
    } else {                             // Wct
        int n = b - 1536;
        unsigned short* dst = Wct + (size_t)n * KPC;
        for (int t = threadIdx.x; t < KPC; t += 256) {
            int ch = t >> 5, s = (t >> 3) & 3, j = t & 7;
            int gk = ch * 32 + ((s ^ (n & 3)) * 8) + j;
            float v = (gk < DIN) ? Wc[(size_t)gk * 256 + n] : 0.0f;
            dst[t] = f2bf(v);
        }
    }
}

// ---------------- cf prep: fp32 -> LINEAR bf16 rows [NC][320] (coalesced both sides) ----------------
__global__ __launch_bounds__(256) void cf_prep_kernel(
    const float* __restrict__ cf, unsigned short* __restrict__ cfb)
{
    const int blk = blockIdx.x;               // 16 nodes/block, NC/16 = 3125
    const int base = blk * 16 * DIN;          // element offset (16*313*4 B = 16B-aligned)
    for (int i = threadIdx.x; i < 1252; i += 256) {   // 16*313/4
        float4 v = *(const float4*)(cf + base + i * 4);
        int f0 = i * 4;
        #pragma unroll
        for (int j = 0; j < 4; ++j) {
            int f = f0 + j;
            int n = f / DIN, k = f - n * DIN;
            cfb[(size_t)(blk * 16 + n) * KPC + k] = f2bf(((const float*)&v)[j]);
        }
    }
    for (int i = threadIdx.x; i < 16 * (KPC - DIN); i += 256) {
        int n = i / (KPC - DIN), k = DIN + i % (KPC - DIN);
        cfb[(size_t)(blk * 16 + n) * KPC + k] = 0;
    }
}

// ---------------- child encoder (fast): node_gemm clone, A reg-staged from linear cfb ----------------
__global__ __launch_bounds__(256, 3) void child_fast_kernel(
    const unsigned short* __restrict__ cfb, const float* __restrict__ exists,
    const unsigned short* __restrict__ Wct, const float* __restrict__ bias,
    unsigned short* __restrict__ xb, float* __restrict__ pmax)
{
    __shared__ unsigned short sA[2][64][40];   // padded, reg-staged (no XOR on A)
    __shared__ unsigned short sB[2][256][32];  // gload_lds, XOR via Wct prep
    __shared__ float smax[256];

    const int tid = threadIdx.x, lane = tid & 63, wid = tid >> 6;
    const int wm = wid >> 1, wn = wid & 1, l15 = lane & 15, l4 = lane >> 4;
    const int node0 = blockIdx.x * 64;
    const int arow = tid >> 2, s3 = tid & 3;

    smax[tid] = 0.0f;

    int nodeA = node0 + arow; if (nodeA >= NC) nodeA = NC - 1;

    f32x4 acc[2][8];
    #pragma unroll
    for (int mi = 0; mi < 2; ++mi)
        #pragma unroll
        for (int ni = 0; ni < 8; ++ni)
            acc[mi][ni] = (f32x4){0.f, 0.f, 0.f, 0.f};

    #pragma unroll
    for (int i = 0; i < 4; ++i) {
        int n = (wid << 6) + (i << 4) + (lane >> 2);
        gload_lds16(Wct + (size_t)n * KPC + (lane & 3) * 8, &sB[0][(wid << 6) + (i << 4)][0]);
    }
    *(int4*)&sA[0][arow][s3 * 8] = *(const int4*)(cfb + (size_t)nodeA * KPC + s3 * 8);
    __syncthreads();

    int buf = 0;
    for (int ch = 0; ch < 10; ++ch) {
        const int nch = ch + 1;
        int4 areg;
        if (nch < 10) {
            #pragma unroll
            for (int i = 0; i < 4; ++i) {
                int n = (wid << 6) + (i << 4) + (lane >> 2);
                gload_lds16(Wct + (size_t)n * KPC + nch * 32 + (lane & 3) * 8,
                            &sB[buf ^ 1][(wid << 6) + (i << 4)][0]);
            }
            areg = *(const int4*)(cfb + (size_t)nodeA * KPC + nch * 32 + s3 * 8);
        }
        bf16x8 af[2];
        #pragma unroll
        for (int mi = 0; mi < 2; ++mi)
            af[mi] = *(const bf16x8*)&sA[buf][wm * 32 + mi * 16 + l15][l4 * 8];
        #pragma unroll
        for (int ni = 0; ni < 8; ++ni) {
            int n = wn * 128 + ni * 16 + l15;
            bf16x8 bfr = *(const bf16x8*)&sB[buf][n][(l4 ^ (n & 3)) * 8];
            acc[0][ni] = __builtin_amdgcn_mfma_f32_16x16x32_bf16(af[0], bfr, acc[0][ni], 0, 0, 0);
            acc[1][ni] = __builtin_amdgcn_mfma_f32_16x16x32_bf16(af[1], bfr, acc[1][ni], 0, 0, 0);
        }
        if (nch < 10) *(int4*)&sA[buf ^ 1][arow][s3 * 8] = areg;
        __syncthreads();
        buf ^= 1;
    }

    float bv[8];
    #pragma unroll
    for (int ni = 0; ni < 8; ++ni) bv[ni] = bias[wn * 128 + ni * 16 + l15];
    float cmax[8];
    #pragma unroll
    for (int ni = 0; ni < 8; ++ni) cmax[ni] = 0.0f;

    #pragma unroll
    for (int mi = 0; mi < 2; ++mi) {
        #pragma unroll
        for (int r = 0; r < 4; ++r) {
            int node = node0 + wm * 32 + mi * 16 + l4 * 4 + r;
            if (node < NC) {
                float ex = exists[node];
                #pragma unroll
                for (int ni = 0; ni < 8; ++ni) {
                    float v = fmaxf(acc[mi][ni][r] + bv[ni], 0.f) * ex;
                    xb[(size_t)node * 256 + wn * 128 + ni * 16 + l15] = f2bf(v);
                    cmax[ni] = fmaxf(cmax[ni], v);
                }
            }
        }
    }
    #pragma unroll
    for (int ni = 0; ni < 8; ++ni)
        atomicMax((unsigned int*)&smax[wn * 128 + ni * 16 + l15], __float_as_uint(cmax[ni]));
    __syncthreads();
    atomicMax((unsigned int*)&pmax[tid], __float_as_uint(smax[tid]));
}

// ---------------- child encoder (fallback, original): scalar fp32 A staging ----------------
__global__ __launch_bounds__(256, 4) void child_mfma_kernel(
    const float* __restrict__ cf, const float* __restrict__ exists,
    const unsigned short* __restrict__ Wct, const float* __restrict__ bias,
    unsigned short* __restrict__ xb, float* __restrict__ pmax)
{
    __shared__ unsigned short sA[64][40];
    __shared__ unsigned short sB[256][32];
    __shared__ float smax[256];

    const int tid = threadIdx.x, lane = tid & 63, wid = tid >> 6;
    const int wm = wid >> 1, wn = wid & 1, l15 = lane & 15, l4 = lane >> 4;
    const int node0 = blockIdx.x * 64;
    const int arow = tid >> 2, s3 = tid & 3;

    smax[tid] = 0.0f;

    f32x4 acc[2][8];
    #pragma unroll
    for (int mi = 0; mi < 2; ++mi)
        #pragma unroll
        for (int ni = 0; ni < 8; ++ni)
            acc[mi][ni] = (f32x4){0.f, 0.f, 0.f, 0.f};

    int nodeA = node0 + arow; if (nodeA >= NC) nodeA = NC - 1;

    for (int ch = 0; ch < 10; ++ch) {
        #pragma unroll
        for (int i = 0; i < 4; ++i) {
            int n = (wid << 6) + (i << 4) + (lane >> 2);
            gload_lds16(Wct + (size_t)n * KPC + ch * 32 + (lane & 3) * 8,
                        &sB[(wid << 6) + (i << 4)][0]);
        }
        {
            int gk0 = ch * 32 + s3 * 8;
            union { unsigned short u[8]; int4 v; } pk;
            #pragma unroll
            for (int j = 0; j < 8; ++j) {
                int gk = gk0 + j;
                float f = (gk < DIN) ? cf[(size_t)nodeA * DIN + gk] : 0.0f;
                pk.u[j] = f2bf(f);
            }
            *(int4*)&sA[arow][s3 * 8] = pk.v;
        }
        __syncthreads();
        bf16x8 af[2];
        #pragma unroll
        for (int mi = 0; mi < 2; ++mi)
            af[mi] = *(const bf16x8*)&sA[wm * 32 + mi * 16 + l15][l4 * 8];
        #pragma unroll
        for (int ni = 0; ni < 8; ++ni) {
            int n = wn * 128 + ni * 16 + l15;
            bf16x8 bfr = *(const bf16x8*)&sB[n][(l4 ^ (n & 3)) * 8];
            acc[0][ni] = __builtin_amdgcn_mfma_f32_16x16x32_bf16(af[0], bfr, acc[0][ni], 0, 0, 0);
            acc[1][ni] = __builtin_amdgcn_mfma_f32_16x16x32_bf16(af[1], bfr, acc[1][ni], 0, 0, 0);
        }
        __syncthreads();
    }

    float bv[8];
    #pragma unroll
    for (int ni = 0; ni < 8; ++ni) bv[ni] = bias[wn * 128 + ni * 16 + l15];
    float cmax[8];
    #pragma unroll
    for (int ni = 0; ni < 8; ++ni) cmax[ni] = 0.0f;

    #pragma unroll
    for (int mi = 0; mi < 2; ++mi) {
        #pragma unroll
        for (int r = 0; r < 4; ++r) {
            int node = node0 + wm * 32 + mi * 16 + l4 * 4 + r;
            if (node < NC) {
                float ex = exists[node];
                #pragma unroll
                for (int ni = 0; ni < 8; ++ni) {
                    float v = fmaxf(acc[mi][ni][r] + bv[ni], 0.f) * ex;
                    xb[(size_t)node * 256 + wn * 128 + ni * 16 + l15] = f2bf(v);
                    cmax[ni] = fmaxf(cmax[ni], v);
                }
            }
        }
    }
    #pragma unroll
    for (int ni = 0; ni < 8; ++ni)
        atomicMax((unsigned int*)&smax[wn * 128 + ni * 16 + l15], __float_as_uint(cmax[ni]));
    __syncthreads();
    atomicMax((unsigned int*)&pmax[tid], __float_as_uint(smax[tid]));
}

// ---------------- node GEMM (A from bf16 xb) ----------------
__global__ __launch_bounds__(256, 3) void node_gemm_kernel(
    const unsigned short* __restrict__ xb,
    const unsigned short* __restrict__ Wpt,
    unsigned short* __restrict__ yp)
{
    __shared__ unsigned short sA[2][64][40];
    __shared__ unsigned short sB[2][256][32];

    const int tid = threadIdx.x, lane = tid & 63, wid = tid >> 6;
    const int wm = wid >> 1, wn = wid & 1, l15 = lane & 15, l4 = lane >> 4;
    const int node0 = blockIdx.x * 64;
    const int n0 = blockIdx.y * 256;
    const int arow = tid >> 2, s3 = tid & 3;

    int nodeA = node0 + arow; if (nodeA >= NC) nodeA = NC - 1;

    f32x4 acc[2][8];
    #pragma unroll
    for (int mi = 0; mi < 2; ++mi)
        #pragma unroll
        for (int ni = 0; ni < 8; ++ni)
            acc[mi][ni] = (f32x4){0.f, 0.f, 0.f, 0.f};

    #pragma unroll
    for (int i = 0; i < 4; ++i) {
        int n = (wid << 6) + (i << 4) + (lane >> 2);
        gload_lds16(Wpt + (size_t)(n0 + n) * 256 + (lane & 3) * 8, &sB[0][(wid << 6) + (i << 4)][0]);
    }
    *(int4*)&sA[0][arow][s3 * 8] = *(const int4*)(xb + (size_t)nodeA * 256 + s3 * 8);
    __syncthreads();

    int buf = 0;
    for (int ch = 0; ch < 8; ++ch) {
        const int nch = ch + 1;
        int4 areg;
        if (nch < 8) {
            #pragma unroll
            for (int i = 0; i < 4; ++i) {
                int n = (wid << 6) + (i << 4) + (lane >> 2);
                gload_lds16(Wpt + (size_t)(n0 + n) * 256 + nch * 32 + (lane & 3) * 8,
                            &sB[buf ^ 1][(wid << 6) + (i << 4)][0]);
            }
            areg = *(const int4*)(xb + (size_t)nodeA * 256 + nch * 32 + s3 * 8);
        }
        bf16x8 af[2];
        #pragma unroll
        for (int mi = 0; mi < 2; ++mi)
            af[mi] = *(const bf16x8*)&sA[buf][wm * 32 + mi * 16 + l15][l4 * 8];
        #pragma unroll
        for (int ni = 0; ni < 8; ++ni) {
            int n = wn * 128 + ni * 16 + l15;
            bf16x8 bfr = *(const bf16x8*)&sB[buf][n][(l4 ^ (n & 3)) * 8];
            acc[0][ni] = __builtin_amdgcn_mfma_f32_16x16x32_bf16(af[0], bfr, acc[0][ni], 0, 0, 0);
            acc[1][ni] = __builtin_amdgcn_mfma_f32_16x16x32_bf16(af[1], bfr, acc[1][ni], 0, 0, 0);
        }
        if (nch < 8) *(int4*)&sA[buf ^ 1][arow][s3 * 8] = areg;
        __syncthreads();
        buf ^= 1;
    }

    #pragma unroll
    for (int mi = 0; mi < 2; ++mi) {
        #pragma unroll
        for (int r = 0; r < 4; ++r) {
            int node = node0 + wm * 32 + mi * 16 + l4 * 4 + r;
            if (node < NC) {
                #pragma unroll
                for (int ni = 0; ni < 8; ++ni)
                    yp[(size_t)node * 512 + n0 + wn * 128 + ni * 16 + l15] = f2bf(acc[mi][ni][r]);
            }
        }
    }
}

// ---------------- node GEMM, A = bf16(accb * inv); also folds iter-0 pmax ----------------
__global__ __launch_bounds__(256, 3) void node_gemm_scaled_kernel(
    const float* __restrict__ accb, const float* __restrict__ invv,
    const unsigned short* __restrict__ Wpt,
    unsigned short* __restrict__ yp, float* __restrict__ pmax0)
{
    __shared__ unsigned short sA[2][64][40];
    __shared__ unsigned short sB[2][256][32];
    __shared__ float smax[256];

    const int tid = threadIdx.x, lane = tid & 63, wid = tid >> 6;
    const int wm = wid >> 1, wn = wid & 1, l15 = lane & 15, l4 = lane >> 4;
    const int node0 = blockIdx.x * 64;
    const int n0 = blockIdx.y * 256;
    const int arow = tid >> 2, s3 = tid & 3;

    smax[tid] = 0.0f;

    int nodeA = node0 + arow; if (nodeA >= NC) nodeA = NC - 1;
    const float inv_n = invv[nodeA];

    f32x4 acc[2][8];
    #pragma unroll
    for (int mi = 0; mi < 2; ++mi)
        #pragma unroll
        for (int ni = 0; ni < 8; ++ni)
            acc[mi][ni] = (f32x4){0.f, 0.f, 0.f, 0.f};

    #pragma unroll
    for (int i = 0; i < 4; ++i) {
        int n = (wid << 6) + (i << 4) + (lane >> 2);
        gload_lds16(Wpt + (size_t)(n0 + n) * 256 + (lane & 3) * 8, &sB[0][(wid << 6) + (i << 4)][0]);
    }
    {
        float4 a0 = *(const float4*)(accb + (size_t)nodeA * 256 + s3 * 8);
        float4 a1 = *(const float4*)(accb + (size_t)nodeA * 256 + s3 * 8 + 4);
        float v0=a0.x*inv_n, v1=a0.y*inv_n, v2=a0.z*inv_n, v3=a0.w*inv_n;
        float v4=a1.x*inv_n, v5=a1.y*inv_n, v6=a1.z*inv_n, v7=a1.w*inv_n;
        union { unsigned short u[8]; int4 v; } pk;
        pk.u[0]=f2bf(v0); pk.u[1]=f2bf(v1); pk.u[2]=f2bf(v2); pk.u[3]=f2bf(v3);
        pk.u[4]=f2bf(v4); pk.u[5]=f2bf(v5); pk.u[6]=f2bf(v6); pk.u[7]=f2bf(v7);
        *(int4*)&sA[0][arow][s3 * 8] = pk.v;
        int c0 = s3 * 8;
        atomicMax((unsigned int*)&smax[c0+0], __float_as_uint(v0));
        atomicMax((unsigned int*)&smax[c0+1], __float_as_uint(v1));
        atomicMax((unsigned int*)&smax[c0+2], __float_as_uint(v2));
        atomicMax((unsigned int*)&smax[c0+3], __float_as_uint(v3));
        atomicMax((unsigned int*)&smax[c0+4], __float_as_uint(v4));
        atomicMax((unsigned int*)&smax[c0+5], __float_as_uint(v5));
        atomicMax((unsigned int*)&smax[c0+6], __float_as_uint(v6));
        atomicMax((unsigned int*)&smax[c0+7], __float_as_uint(v7));
    }
    __syncthreads();

    int buf = 0;
    for (int ch = 0; ch < 8; ++ch) {
        const int nch = ch + 1;
        float4 f4a, f4b;
        if (nch < 8) {
            #pragma unroll
            for (int i = 0; i < 4; ++i) {
                int n = (wid << 6) + (i << 4) + (lane >> 2);
                gload_lds16(Wpt + (size_t)(n0 + n) * 256 + nch * 32 + (lane & 3) * 8,
                            &sB[buf ^ 1][(wid << 6) + (i << 4)][0]);
            }
            f4a = *(const float4*)(accb + (size_t)nodeA * 256 + nch * 32 + s3 * 8);
            f4b = *(const float4*)(accb + (size_t)nodeA * 256 + nch * 32 + s3 * 8 + 4);
        }
        bf16x8 af[2];
        #pragma unroll
        for (int mi = 0; mi < 2; ++mi)
            af[mi] = *(const bf16x8*)&sA[buf][wm * 32 + mi * 16 + l15][l4 * 8];
        #pragma unroll
        for (int ni = 0; ni < 8; ++ni) {
            int n = wn * 128 + ni * 16 + l15;
            bf16x8 bfr = *(const bf16x8*)&sB[buf][n][(l4 ^ (n & 3)) * 8];
            acc[0][ni] = __builtin_amdgcn_mfma_f32_16x16x32_bf16(af[0], bfr, acc[0][ni], 0, 0, 0);
            acc[1][ni] = __builtin_amdgcn_mfma_f32_16x16x32_bf16(af[1], bfr, acc[1][ni], 0, 0, 0);
        }
        if (nch < 8) {
            float v0=f4a.x*inv_n, v1=f4a.y*inv_n, v2=f4a.z*inv_n, v3=f4a.w*inv_n;
            float v4=f4b.x*inv_n, v5=f4b.y*inv_n, v6=f4b.z*inv_n, v7=f4b.w*inv_n;
            union { unsigned short u[8]; int4 v; } pk;
            pk.u[0]=f2bf(v0); pk.u[1]=f2bf(v1); pk.u[2]=f2bf(v2); pk.u[3]=f2bf(v3);
            pk.u[4]=f2bf(v4); pk.u[5]=f2bf(v5); pk.u[6]=f2bf(v6); pk.u[7]=f2bf(v7);
            *(int4*)&sA[buf ^ 1][arow][s3 * 8] = pk.v;
            int c0 = nch * 32 + s3 * 8;
            atomicMax((unsigned int*)&smax[c0+0], __float_as_uint(v0));
            atomicMax((unsigned int*)&smax[c0+1], __float_as_uint(v1));
            atomicMax((unsigned int*)&smax[c0+2], __float_as_uint(v2));
            atomicMax((unsigned int*)&smax[c0+3], __float_as_uint(v3));
            atomicMax((unsigned int*)&smax[c0+4], __float_as_uint(v4));
            atomicMax((unsigned int*)&smax[c0+5], __float_as_uint(v5));
            atomicMax((unsigned int*)&smax[c0+6], __float_as_uint(v6));
            atomicMax((unsigned int*)&smax[c0+7], __float_as_uint(v7));
        }
        __syncthreads();
        buf ^= 1;
    }

    #pragma unroll
    for (int mi = 0; mi < 2; ++mi) {
        #pragma unroll
        for (int r = 0; r < 4; ++r) {
            int node = node0 + wm * 32 + mi * 16 + l4 * 4 + r;
            if (node < NC) {
                #pragma unroll
                for (int ni = 0; ni < 8; ++ni)
                    yp[(size_t)node * 512 + n0 + wn * 128 + ni * 16 + l15] = f2bf(acc[mi][ni][r]);
            }
        }
    }
    atomicMax((unsigned int*)&pmax0[tid], __float_as_uint(smax[tid]));
}

// ---------------- counting sort of edges by src ----------------
__global__ __launch_bounds__(256) void count_int_kernel(
    const int* __restrict__ eidx, int* __restrict__ icnt)
{
    int t = blockIdx.x * 256 + threadIdx.x;
    if (t < NE) atomicAdd(&icnt[eidx[2 * t]], 1);
}

__global__ __launch_bounds__(256) void scan1_kernel(
    const int* __restrict__ icnt, int* __restrict__ part)
{
    __shared__ int sd[256];
    int i = blockIdx.x * 256 + threadIdx.x;
    sd[threadIdx.x] = (i < NC) ? icnt[i] : 0;
    __syncthreads();
    for (int d = 128; d > 0; d >>= 1) {
        if (threadIdx.x < d) sd[threadIdx.x] += sd[threadIdx.x + d];
        __syncthreads();
    }
    if (threadIdx.x == 0) part[blockIdx.x] = sd[0];
}

__global__ void scan2_kernel(int* __restrict__ part)
{
    if (threadIdx.x == 0) {
        int acc = 0;
        for (int i = 0; i < NB_SCAN; ++i) { int v = part[i]; part[i] = acc; acc += v; }
    }
}

__global__ __launch_bounds__(256) void scan3_kernel(
    const int* __restrict__ icnt, const int* __restrict__ part,
    int* __restrict__ cur)
{
    __shared__ int sc[256];
    const int t = threadIdx.x;
    int i = blockIdx.x * 256 + t;
    int val = (i < NC) ? icnt[i] : 0;
    sc[t] = val;
    __syncthreads();
    for (int d = 1; d < 256; d <<= 1) {
        int x = (t >= d) ? sc[t - d] : 0;
        __syncthreads();
        sc[t] += x;
        __syncthreads();
    }
    if (i < NC) cur[i] = part[blockIdx.x] + sc[t] - val;
}

__global__ __launch_bounds__(256) void bin_kernel(
    const int* __restrict__ eidx, int* __restrict__ cur, int* __restrict__ perm)
{
    int t = blockIdx.x * 256 + threadIdx.x;
    if (t < NE) {
        int s = eidx[2 * t];
        int p = atomicAdd(&cur[s], 1);
        perm[p] = t;
    }
}

__global__ __launch_bounds__(256) void inv_kernel(
    const int* __restrict__ icnt, float* __restrict__ inv)
{
    int t = blockIdx.x * 256 + threadIdx.x;
    if (t < NC) inv[t] = 1.0f / fmaxf((float)icnt[t], 1.0f);
}

// ---------------- ef prep: bf16, sorted edge order, chunk-major; pre-permuted src/dst ----
__global__ __launch_bounds__(256) void ef_prep_kernel(
    const float* __restrict__ eto, const float* __restrict__ efe,
    const int* __restrict__ perm, const int* __restrict__ eidx,
    unsigned short* __restrict__ efc01, unsigned short* __restrict__ efc2,
    int* __restrict__ esrc, int* __restrict__ edst)
{
    int p = blockIdx.x * 256 + threadIdx.x;
    if (p >= NE) return;
    int e = perm[p];
    esrc[p] = eidx[2 * e];
    edst[p] = eidx[2 * e + 1];
    const float* efr = efe + (size_t)e * 64;

    union { unsigned short u[8]; int4 v; } pk;
    {
        float4 a = *(const float4*)(eto + (size_t)e * 4);
        float4 b = *(const float4*)(efr + 0);
        pk.u[0]=f2bf(a.x); pk.u[1]=f2bf(a.y); pk.u[2]=f2bf(a.z); pk.u[3]=f2bf(a.w);
        pk.u[4]=f2bf(b.x); pk.u[5]=f2bf(b.y); pk.u[6]=f2bf(b.z); pk.u[7]=f2bf(b.w);
        *(int4*)(efc01 + (size_t)p * 32) = pk.v;
    }
    #pragma unroll
    for (int g = 1; g < 4; ++g) {
        float4 a = *(const float4*)(efr + g * 8 - 4);
        float4 b = *(const float4*)(efr + g * 8);
        pk.u[0]=f2bf(a.x); pk.u[1]=f2bf(a.y); pk.u[2]=f2bf(a.z); pk.u[3]=f2bf(a.w);
        pk.u[4]=f2bf(b.x); pk.u[5]=f2bf(b.y); pk.u[6]=f2bf(b.z); pk.u[7]=f2bf(b.w);
        *(int4*)(efc01 + (size_t)p * 32 + g * 8) = pk.v;
    }
    #pragma unroll
    for (int g = 0; g < 4; ++g) {
        float4 a = *(const float4*)(efr + 28 + g * 8);
        float4 b = *(const float4*)(efr + 32 + g * 8);
        pk.u[0]=f2bf(a.x); pk.u[1]=f2bf(a.y); pk.u[2]=f2bf(a.z); pk.u[3]=f2bf(a.w);
        pk.u[4]=f2bf(b.x); pk.u[5]=f2bf(b.y); pk.u[6]=f2bf(b.z); pk.u[7]=f2bf(b.w);
        *(int4*)(efc01 + ((size_t)NEP + p) * 32 + g * 8) = pk.v;
    }
    {
        float4 a = *(const float4*)(efr + 60);
        pk.u[0]=f2bf(a.x); pk.u[1]=f2bf(a.y); pk.u[2]=f2bf(a.z); pk.u[3]=f2bf(a.w);
        pk.u[4]=0; pk.u[5]=0; pk.u[6]=0; pk.u[7]=0;
        *(int4*)(efc2 + (size_t)p * 8) = pk.v;
    }
}

// gather + walk macros (independent loads, no cross-row state; rule #20 safe)
#define LOAD16(B, YT, YM)                                              \
    _Pragma("unroll")                                                  \
    for (int r = 0; r < 16; ++r) {                                     \
        int row = (B) * 16 + r;                                        \
        YT[r] = bf2f(yp[((unsigned)s_src[row] << 9) + (unsigned)col]); \
        YM[r] = bf2f(yp[((unsigned)s_dst[row] << 9) + 256u + (unsigned)col]); \
    }

#define WALK16(B, YT, YM)                                              \
    _Pragma("unroll")                                                  \
    for (int r = 0; r < 16; ++r) {                                     \
        int row = (B) * 16 + r;                                        \
        float v = 0.0f;                                                \
        if (e0 + row < NE)                                             \
            v = fmaxf(bf2f(epb[row][col]) + YT[r] + YM[r] + b_col, 0.f); \
        int sr = s_src[row];                                           \
        if (sr != curn) {                                              \
            if (rstart > 0) accb[(size_t)curn * 256 + col] = run;      \
            else            atomicAdd(&accb[(size_t)curn * 256 + col], run); \
            curn = sr; run = v; rstart = row;                          \
        } else {                                                       \
            run += v;                                                  \
        }                                                              \
    }

// ---------------- combine (efc path): single-sW MFMA + one-shot bf16 ep staging +
//                  barrier-free 64-row walk with depth-2 pipelined gathers ----------------
__global__ __launch_bounds__(256, 4) void combine_efc_kernel(
    const unsigned short* __restrict__ yp,
    const unsigned short* __restrict__ efc01,
    const unsigned short* __restrict__ efc2,
    const int* __restrict__ esrc, const int* __restrict__ edst,
    const unsigned short* __restrict__ Wbt,
    const float* __restrict__ bias,
    float* __restrict__ accb)
{
    __shared__ __align__(16) unsigned char smem[34816];
    unsigned short (*sA01)[64][32] = (unsigned short (*)[64][32])(smem);
    unsigned short (*sA2)[8]       = (unsigned short (*)[8])(smem + 8192);
    unsigned short (*sW)[32]       = (unsigned short (*)[32])(smem + 9216);
    unsigned short (*epb)[272]     = (unsigned short (*)[272])(smem);
    __shared__ int s_src[64], s_dst[64];

    const int tid = threadIdx.x;
    const int nwg = gridDim.x;
    const int q = nwg >> 3, rr = nwg & 7;
    const int xcd = blockIdx.x & 7, within = blockIdx.x >> 3;
    const int bid = (xcd < rr ? xcd * (q + 1) : rr * (q + 1) + (xcd - rr) * q) + within;
    const int e0 = bid * 64;

    const int lane = tid & 63;
    const int wid  = tid >> 6;
    const int wm   = wid >> 1;
    const int wn   = wid & 1;
    const int l15  = lane & 15;
    const int l4   = lane >> 4;

    if (tid < 64) {
        int e = e0 + tid; if (e > NE - 1) e = NE - 1;
        s_src[tid] = esrc[e];
        s_dst[tid] = edst[e];
    }
    gload_lds16(efc01 + ((size_t)e0 + wid * 16) * 32 + lane * 8, &sA01[0][wid * 16][0]);
    gload_lds16(efc01 + ((size_t)NEP + e0 + wid * 16) * 32 + lane * 8, &sA01[1][wid * 16][0]);
    if (wid == 0)
        gload_lds16(efc2 + (size_t)e0 * 8 + lane * 8, &sA2[0][0]);
    #pragma unroll
    for (int i = 0; i < 4; ++i) {
        gload_lds16(Wbt + (size_t)((wid << 6) + (i << 4) + (lane >> 2)) * KB + (lane & 3) * 8,
                    &sW[(wid << 6) + (i << 4)][0]);
    }
    __syncthreads();

    f32x4 acc[2][8];
    #pragma unroll
    for (int mi = 0; mi < 2; ++mi)
        #pragma unroll
        for (int ni = 0; ni < 8; ++ni)
            acc[mi][ni] = (f32x4){0.f, 0.f, 0.f, 0.f};

    #pragma unroll
    for (int ch = 0; ch < 3; ++ch) {
        if (ch > 0) {
            __syncthreads();
            #pragma unroll
            for (int i = 0; i < 4; ++i) {
                gload_lds16(Wbt + (size_t)((wid << 6) + (i << 4) + (lane >> 2)) * KB + ch * 32 + (lane & 3) * 8,
                            &sW[(wid << 6) + (i << 4)][0]);
            }
            __syncthreads();
        }
        bf16x8 af0, af1;
        if (ch < 2) {
            af0 = *(const bf16x8*)&sA01[ch][wm * 32 + l15][l4 * 8];
            af1 = *(const bf16x8*)&sA01[ch][wm * 32 + 16 + l15][l4 * 8];
        } else {
            bf16x8 z = (bf16x8){0,0,0,0,0,0,0,0};
            bf16x8 a0 = *(const bf16x8*)&sA2[wm * 32 + l15][0];
            bf16x8 a1 = *(const bf16x8*)&sA2[wm * 32 + 16 + l15][0];
            af0 = (l4 == 0) ? a0 : z;
            af1 = (l4 == 0) ? a1 : z;
        }
        #pragma unroll
        for (int ni = 0; ni < 8; ++ni) {
            int n = wn * 128 + ni * 16 + l15;
            bf16x8 bfr = *(const bf16x8*)&sW[n][(l4 ^ (n & 3)) * 8];
            acc[0][ni] = __builtin_amdgcn_mfma_f32_16x16x32_bf16(af0, bfr, acc[0][ni], 0, 0, 0);
            acc[1][ni] = __builtin_amdgcn_mfma_f32_16x16x32_bf16(af1, bfr, acc[1][ni], 0, 0, 0);
        }
    }
    __syncthreads();

    // one-shot staging: whole 64x256 tile to bf16 LDS; acc dies here
    #pragma unroll
    for (int mi = 0; mi < 2; ++mi)
        #pragma unroll
        for (int ni = 0; ni < 8; ++ni)
            #pragma unroll
            for (int r = 0; r < 4; ++r)
                epb[wm * 32 + mi * 16 + l4 * 4 + r][wn * 128 + ni * 16 + l15] = f2bf(acc[mi][ni][r]);

    const int col = tid;
    const float b_col = bias[col];
    float ytA[16], ymA[16], ytB[16], ymB[16];
    LOAD16(0, ytA, ymA)
    LOAD16(1, ytB, ymB)
    __syncthreads();   // epb visible

    int curn = s_src[0];
    int rstart = 0;
    float run = 0.f;

    WALK16(0, ytA, ymA)
    LOAD16(2, ytA, ymA)
    WALK16(1, ytB, ymB)
    LOAD16(3, ytB, ymB)
    WALK16(2, ytA, ymA)
    WALK16(3, ytB, ymB)

    atomicAdd(&accb[(size_t)curn * 256 + col], run);
}

// ---------------- combine (fallback, R8-exact): fp32 ef staging via perm ----------------
__global__ __launch_bounds__(256, 3) void combine_f32_kernel(
    const unsigned short* __restrict__ yp,
    const float* __restrict__ eto, const float* __restrict__ efe,
    const int* __restrict__ eidx, const int* __restrict__ perm,
    const unsigned short* __restrict__ Wbt,
    const float* __restrict__ bias,
    float* __restrict__ accb)
{
    __shared__ unsigned short sA[3][64][40];
    __shared__ unsigned short sW[2][256][32];
    __shared__ int s_src[64], s_dst[64], s_perm[64];

    const int tid = threadIdx.x;
    const int nwg = gridDim.x;
    const int q = nwg >> 3, rr = nwg & 7;
    const int xcd = blockIdx.x & 7, within = blockIdx.x >> 3;
    const int bid = (xcd < rr ? xcd * (q + 1) : rr * (q + 1) + (xcd - rr) * q) + within;
    const int e0 = bid * 64;

    if (tid < 64) {
        int ee = e0 + tid; if (ee >= NE) ee = NE - 1;
        int e = perm[ee];
        s_perm[tid] = e;
        s_src[tid] = eidx[2 * e];
        s_dst[tid] = eidx[2 * e + 1];
    }
    const int lane = tid & 63;
    const int wid  = tid >> 6;
    const int wm   = wid >> 1;
    const int wn   = wid & 1;
    const int l15  = lane & 15;
    const int l4   = lane >> 4;
    const int arow = tid >> 2;
    const int s3   = tid & 3;

    f32x4 acc[2][8];
    #pragma unroll
    for (int mi = 0; mi < 2; ++mi)
        #pragma unroll
        for (int ni = 0; ni < 8; ++ni)
            acc[mi][ni] = (f32x4){0.f, 0.f, 0.f, 0.f};

    #pragma unroll
    for (int i = 0; i < 4; ++i) {
        int n = (wid << 6) + (i << 4) + (lane >> 2);
        gload_lds16(Wbt + (size_t)n * KB + (lane & 3) * 8, &sW[0][(wid << 6) + (i << 4)][0]);
    }
    __syncthreads();

    const int my_e = s_perm[arow];
    #pragma unroll
    for (int ch = 0; ch < 3; ++ch) {
        int g0 = ch * 32 + s3 * 8;
        union { unsigned short u[8]; int4 v; } pk;
        #pragma unroll
        for (int j = 0; j < 8; ++j) {
            int g = g0 + j;
            float f = 0.0f;
            if (g < 4)       f = eto[(size_t)my_e * 4 + g];
            else if (g < 68) f = efe[(size_t)my_e * 64 + (g - 4)];
            pk.u[j] = f2bf(f);
        }
        *(int4*)&sA[ch][arow][s3 * 8] = pk.v;
    }
    __syncthreads();

    int buf = 0;
    #pragma unroll
    for (int ch = 0; ch < 3; ++ch) {
        if (ch + 1 < 3) {
            #pragma unroll
            for (int i = 0; i < 4; ++i) {
                int n = (wid << 6) + (i << 4) + (lane >> 2);
                gload_lds16(Wbt + (size_t)n * KB + (ch + 1) * 32 + (lane & 3) * 8,
                            &sW[buf ^ 1][(wid << 6) + (i << 4)][0]);
            }
        }
        bf16x8 af[2];
        #pragma unroll
        for (int mi = 0; mi < 2; ++mi)
            af[mi] = *(const bf16x8*)&sA[ch][wm * 32 + mi * 16 + l15][l4 * 8];
        #pragma unroll
        for (int ni = 0; ni < 8; ++ni) {
            int n = wn * 128 + ni * 16 + l15;
            bf16x8 bfr = *(const bf16x8*)&sW[buf][n][(l4 ^ (n & 3)) * 8];
            acc[0][ni] = __builtin_amdgcn_mfma_f32_16x16x32_bf16(af[0], bfr, acc[0][ni], 0, 0, 0);
            acc[1][ni] = __builtin_amdgcn_mfma_f32_16x16x32_bf16(af[1], bfr, acc[1][ni], 0, 0, 0);
        }
        __syncthreads();
        buf ^= 1;
    }

    float (*ep)[258] = (float (*)[258])(&sW[0][0][0]);
    const int col = tid;
    const float b_col = bias[col];

    int curn = s_src[0];
    int rstart = 0;
    float run = 0.f;
    #pragma unroll
    for (int c = 0; c < 4; ++c) {
        if (wm == (c >> 1)) {
            const int mi = c & 1;
            #pragma unroll
            for (int ni = 0; ni < 8; ++ni) {
                #pragma unroll
                for (int r = 0; r < 4; ++r)
                    ep[l4 * 4 + r][wn * 128 + ni * 16 + l15] = acc[mi][ni][r];
            }
        }
        float yt[16], ym[16];
        #pragma unroll
        for (int r = 0; r < 16; ++r) {
            int row = c * 16 + r;
            yt[r] = bf2f(yp[(size_t)s_src[row] * 512 + col]);
            ym[r] = bf2f(yp[(size_t)s_dst[row] * 512 + 256 + col]);
        }
        __syncthreads();
        #pragma unroll
        for (int r = 0; r < 16; ++r) {
            int row = c * 16 + r;
            float v = 0.0f;
            if (e0 + row < NE)
                v = fmaxf(ep[r][col] + yt[r] + ym[r] + b_col, 0.f);
            int sr = s_src[row];
            if (sr != curn) {
                if (rstart > 0) accb[(size_t)curn * 256 + col] = run;
                else            atomicAdd(&accb[(size_t)curn * 256 + col], run);
                curn = sr; run = v; rstart = row;
            } else {
                run += v;
            }
        }
        __syncthreads();
    }
    atomicAdd(&accb[(size_t)curn * 256 + col], run);
}

// ---------------- per-node scale + bf16 convert + column max (fallback path) ----------------
__global__ __launch_bounds__(256) void finalize_kernel(
    const float* __restrict__ src, const float* __restrict__ inv,
    unsigned short* __restrict__ xb_out, float* __restrict__ pmax, int n)
{
    const int tid = threadIdx.x;
    int i0 = blockIdx.x * 128;
    int iend = i0 + 128; if (iend > n) iend = n;
    float m = 0.0f;
    for (int i = i0; i < iend; ++i) {
        float v = src[(size_t)i * 256 + tid];
        v *= inv[i];
        xb_out[(size_t)i * 256 + tid] = f2bf(v);
        m = fmaxf(m, v);
    }
    atomicMax((unsigned int*)&pmax[tid], __float_as_uint(m));
}

// ---------------- pmax-only pass (efc path, final layer) ----------------
__global__ __launch_bounds__(256) void pmax_only_kernel(
    const float* __restrict__ src, const float* __restrict__ inv,
    float* __restrict__ pmax, int n)
{
    const int tid = threadIdx.x;
    int i0 = blockIdx.x * 128;
    int iend = i0 + 128; if (iend > n) iend = n;
    float m = 0.0f;
    for (int i = i0; i < iend; ++i)
        m = fmaxf(m, src[(size_t)i * 256 + tid] * inv[i]);
    atomicMax((unsigned int*)&pmax[tid], __float_as_uint(m));
}

__global__ __launch_bounds__(256) void parent_kernel(
    const float* __restrict__ pmax, const float* __restrict__ W,
    const float* __restrict__ bias, float* __restrict__ out)
{
    __shared__ float sp[768];
    const int tid = threadIdx.x;
    for (int i = tid; i < 768; i += 256) sp[i] = pmax[i];
    __syncthreads();
    float s = bias[tid];
    for (int k = 0; k < 768; ++k) s = fmaf(sp[k], W[(size_t)k * 256 + tid], s);
    out[tid] = fmaxf(s, 0.f);
}

extern "C" void kernel_launch(void* const* d_in, const int* in_sizes, int n_in,
                              void* d_out, int out_size, void* d_ws, size_t ws_size,
                              hipStream_t stream)
{
    const float* cf   = (const float*)d_in[0];
    const float* ex   = (const float*)d_in[1];
    const float* eto  = (const float*)d_in[2];
    const float* efe  = (const float*)d_in[3];
    const int*   eidx = (const int*)d_in[4];
    const float* Wc   = (const float*)d_in[5];
    const float* bc   = (const float*)d_in[6];
    const float* W0   = (const float*)d_in[7];
    const float* b0   = (const float*)d_in[8];
    const float* W1   = (const float*)d_in[9];
    const float* b1   = (const float*)d_in[10];
    const float* Wp   = (const float*)d_in[11];
    const float* bp   = (const float*)d_in[12];

    float*          accb = (float*)d_ws;                          // NC*256 f32
    float*          invv = accb + (size_t)NC * 256;               // NC
    float*          pmax = invv + NC;                             // 768
    unsigned short* xb   = (unsigned short*)(pmax + 768);         // NC*256
    unsigned short* yp   = xb + (size_t)NC * 256;                 // NC*512
    unsigned short* Wpt  = yp + (size_t)NC * 512;                 // 2*512*256
    unsigned short* Wbt  = Wpt + (size_t)2 * 512 * 256;           // 2*256*KB
    unsigned short* Wct  = Wbt + (size_t)2 * 256 * KB;            // 256*KPC
    int*            icnt = (int*)(Wct + (size_t)256 * KPC);       // NC
    int*            part = icnt + NC;                             // 256
    int*            curb = part + 256;                            // NC
    int*            perm = curb + NC;                             // NE
    unsigned short* efc01 = (unsigned short*)(perm + NE);         // 2*NEP*32
    unsigned short* efc2  = efc01 + (size_t)2 * NEP * 32;         // NEP*8
    int*            esrc  = (int*)(efc2 + (size_t)NEP * 8);       // NE
    int*            edst  = esrc + NE;                            // NE
    unsigned short* cfb   = (unsigned short*)(edst + NE);         // NC*KPC bf16 (linear)
    size_t need_efc = (size_t)((char*)(edst + NE) - (char*)d_ws);
    size_t need_cfb = (size_t)((char*)(cfb + (size_t)NC * KPC) - (char*)d_ws);
    const bool use_efc = (ws_size >= need_efc);
    const bool use_cfb = (ws_size >= need_cfb);

    hipMemsetAsync(pmax, 0, 768 * sizeof(float), stream);
    hipMemsetAsync(icnt, 0, NC * sizeof(int), stream);

    prep_w_kernel<<<1792, 256, 0, stream>>>(W0, W1, Wc, Wpt, Wbt, Wct);
    if (use_cfb) {
        cf_prep_kernel<<<NC / 16, 256, 0, stream>>>(cf, cfb);
        child_fast_kernel<<<(NC + 63) / 64, 256, 0, stream>>>(cfb, ex, Wct, bc, xb, pmax);
    } else {
        child_mfma_kernel<<<(NC + 63) / 64, 256, 0, stream>>>(cf, ex, Wct, bc, xb, pmax);
    }

    count_int_kernel<<<(NE + 255) / 256, 256, 0, stream>>>(eidx, icnt);
    scan1_kernel<<<NB_SCAN, 256, 0, stream>>>(icnt, part);
    scan2_kernel<<<1, 64, 0, stream>>>(part);
    scan3_kernel<<<NB_SCAN, 256, 0, stream>>>(icnt, part, curb);
    bin_kernel<<<(NE + 255) / 256, 256, 0, stream>>>(eidx, curb, perm);
    inv_kernel<<<(NC + 255) / 256, 256, 0, stream>>>(icnt, invv);
    if (use_efc)
        ef_prep_kernel<<<(NE + 255) / 256, 256, 0, stream>>>(eto, efe, perm, eidx, efc01, efc2, esrc, edst);

    const int nwg = (NE + 63) / 64;
    if (use_efc) {
        // iter 0
        node_gemm_kernel<<<dim3((NC + 63) / 64, 2), 256, 0, stream>>>(xb, Wpt, yp);
        hipMemsetAsync(accb, 0, (size_t)NC * 256 * sizeof(float), stream);
        combine_efc_kernel<<<nwg, 256, 0, stream>>>(
            yp, efc01, efc2, esrc, edst, Wbt, b0, accb);
        // iter 1: A staged from accb*inv (no xb round-trip); iter-0 pmax folded in
        node_gemm_scaled_kernel<<<dim3((NC + 63) / 64, 2), 256, 0, stream>>>(
            accb, invv, Wpt + (size_t)512 * 256, yp, pmax + 256);
        hipMemsetAsync(accb, 0, (size_t)NC * 256 * sizeof(float), stream);
        combine_efc_kernel<<<nwg, 256, 0, stream>>>(
            yp, efc01, efc2, esrc, edst, Wbt + (size_t)256 * KB, b1, accb);
        pmax_only_kernel<<<(NC + 127) / 128, 256, 0, stream>>>(accb, invv, pmax + 512, NC);
    } else {
        for (int it = 0; it < 2; ++it) {
            node_gemm_kernel<<<dim3((NC + 63) / 64, 2), 256, 0, stream>>>(
                xb, Wpt + (size_t)it * 512 * 256, yp);
            hipMemsetAsync(accb, 0, (size_t)NC * 256 * sizeof(float), stream);
            combine_f32_kernel<<<nwg, 256, 0, stream>>>(
                yp, eto, efe, eidx, perm,
                Wbt + (size_t)it * 256 * KB, it ? b1 : b0, accb);
            finalize_kernel<<<(NC + 127) / 128, 256, 0, stream>>>(accb, invv, xb, pmax + 256 * (it + 1), NC);
        }
    }
    parent_kernel<<<1, 256, 0, stream>>>(pmax, Wp, bp, (float*)d_out);
}

// Round 22
// 604.057 us; speedup vs baseline: 1.0338x; 1.0338x over previous
//
#include <hip/hip_runtime.h>

#define NC   50000
#define NE   500000
#define NEP  (NE + 64)
#define DIN  313
#define DNE  580
#define KPC  320          // padded K for child GEMM (10*32)
#define KB   96           // padded K for ef GEMM (3*32)
#define NB_SCAN 196       // ceil(NC/256)

typedef __attribute__((ext_vector_type(8))) short bf16x8;
typedef __attribute__((ext_vector_type(4))) float f32x4;

static __device__ __forceinline__ unsigned short f2bf(float f) {
    unsigned u = __float_as_uint(f);
    unsigned r = (u + 0x7fff + ((u >> 16) & 1)) >> 16;   // RNE
    return (unsigned short)r;
}
static __device__ __forceinline__ float bf2f(unsigned short u) {
    return __uint_as_float(((unsigned)u) << 16);
}
static __device__ __forceinline__ void gload_lds16(const unsigned short* g, unsigned short* l) {
    __builtin_amdgcn_global_load_lds(
        (const __attribute__((address_space(1))) unsigned int*)(g),
        (__attribute__((address_space(3))) unsigned int*)(l), 16, 0, 0);
}

// ---------------- W prep: bf16 transposed, K-chunk XOR-permuted for swizzled gload_lds ----
__global__ __launch_bounds__(256) void prep_w_kernel(
    const float* __restrict__ W0, const float* __restrict__ W1,
    const float* __restrict__ Wc,
    unsigned short* __restrict__ Wpt, unsigned short* __restrict__ Wbt,
    unsigned short* __restrict__ Wct)
{
    int b = blockIdx.x;
    if (b < 1024) {                      // Wpt [layer][n2<512][k<256]
        int layer = b >> 9, n2 = b & 511;
        const float* W = layer ? W1 : W0;
        unsigned short* dst = Wpt + (size_t)layer * 512 * 256 + (size_t)n2 * 256;
        int t = threadIdx.x;
        int ch = t >> 5, s = (t >> 3) & 3, j = t & 7;
        int gk = ch * 32 + ((s ^ (n2 & 3)) * 8) + j;
        float v = (n2 < 256) ? W[(size_t)gk * 256 + n2] : W[(size_t)(256 + gk) * 256 + (n2 - 256)];
        dst[t] = f2bf(v);
    } else if (b < 1536) {               // Wbt [layer][n<256][k<96] XOR-permuted
        int idx = b - 1024;
        int layer = idx >> 8, n = idx & 255;
        const float* W = layer ? W1 : W0;
        unsigned short* dst = Wbt + (size_t)layer * 256 * KB + (size_t)n * KB;
        int t = threadIdx.x;
        if (t < KB) {
            int ch = t >> 5, s = (t >> 3) & 3, j = t & 7;
            int gk = ch * 32 + ((s ^ (n & 3)) * 8) + j;
            float v = (512 + gk < DNE) ? W[(size_t)(512 + gk) * 256 + n] : 0.0f;
            dst[t] = f2bf(v);
        }
    } else {                             // Wct
        int n = b - 1536;
        unsigned short* dst = Wct + (size_t)n * KPC;
        for (int t = threadIdx.x; t < KPC; t += 256) {
            int ch = t >> 5, s = (t >> 3) & 3, j = t & 7;
            int gk = ch * 32 + ((s ^ (n & 3)) * 8) + j;
            float v = (gk < DIN) ? Wc[(size_t)gk * 256 + n] : 0.0f;
            dst[t] = f2bf(v);
        }
    }
}

// ---------------- child encoder (bf16 MFMA) ----------------
__global__ __launch_bounds__(256, 4) void child_mfma_kernel(
    const float* __restrict__ cf, const float* __restrict__ exists,
    const unsigned short* __restrict__ Wct, const float* __restrict__ bias,
    unsigned short* __restrict__ xb, float* __restrict__ pmax)
{
    __shared__ unsigned short sA[64][40];
    __shared__ unsigned short sB[256][32];
    __shared__ float smax[256];

    const int tid = threadIdx.x, lane = tid & 63, wid = tid >> 6;
    const int wm = wid >> 1, wn = wid & 1, l15 = lane & 15, l4 = lane >> 4;
    const int node0 = blockIdx.x * 64;
    const int arow = tid >> 2, s3 = tid & 3;

    smax[tid] = 0.0f;

    f32x4 acc[2][8];
    #pragma unroll
    for (int mi = 0; mi < 2; ++mi)
        #pragma unroll
        for (int ni = 0; ni < 8; ++ni)
            acc[mi][ni] = (f32x4){0.f, 0.f, 0.f, 0.f};

    int nodeA = node0 + arow; if (nodeA >= NC) nodeA = NC - 1;

    for (int ch = 0; ch < 10; ++ch) {
        #pragma unroll
        for (int i = 0; i < 4; ++i) {
            int n = (wid << 6) + (i << 4) + (lane >> 2);
            gload_lds16(Wct + (size_t)n * KPC + ch * 32 + (lane & 3) * 8,
                        &sB[(wid << 6) + (i << 4)][0]);
        }
        {
            int gk0 = ch * 32 + s3 * 8;
            union { unsigned short u[8]; int4 v; } pk;
            #pragma unroll
            for (int j = 0; j < 8; ++j) {
                int gk = gk0 + j;
                float f = (gk < DIN) ? cf[(size_t)nodeA * DIN + gk] : 0.0f;
                pk.u[j] = f2bf(f);
            }
            *(int4*)&sA[arow][s3 * 8] = pk.v;
        }
        __syncthreads();
        bf16x8 af[2];
        #pragma unroll
        for (int mi = 0; mi < 2; ++mi)
            af[mi] = *(const bf16x8*)&sA[wm * 32 + mi * 16 + l15][l4 * 8];
        #pragma unroll
        for (int ni = 0; ni < 8; ++ni) {
            int n = wn * 128 + ni * 16 + l15;
            bf16x8 bfr = *(const bf16x8*)&sB[n][(l4 ^ (n & 3)) * 8];
            acc[0][ni] = __builtin_amdgcn_mfma_f32_16x16x32_bf16(af[0], bfr, acc[0][ni], 0, 0, 0);
            acc[1][ni] = __builtin_amdgcn_mfma_f32_16x16x32_bf16(af[1], bfr, acc[1][ni], 0, 0, 0);
        }
        __syncthreads();
    }

    float bv[8];
    #pragma unroll
    for (int ni = 0; ni < 8; ++ni) bv[ni] = bias[wn * 128 + ni * 16 + l15];
    float cmax[8];
    #pragma unroll
    for (int ni = 0; ni < 8; ++ni) cmax[ni] = 0.0f;

    #pragma unroll
    for (int mi = 0; mi < 2; ++mi) {
        #pragma unroll
        for (int r = 0; r < 4; ++r) {
            int node = node0 + wm * 32 + mi * 16 + l4 * 4 + r;
            if (node < NC) {
                float ex = exists[node];
                #pragma unroll
                for (int ni = 0; ni < 8; ++ni) {
                    float v = fmaxf(acc[mi][ni][r] + bv[ni], 0.f) * ex;
                    xb[(size_t)node * 256 + wn * 128 + ni * 16 + l15] = f2bf(v);
                    cmax[ni] = fmaxf(cmax[ni], v);
                }
            }
        }
    }
    #pragma unroll
    for (int ni = 0; ni < 8; ++ni)
        atomicMax((unsigned int*)&smax[wn * 128 + ni * 16 + l15], __float_as_uint(cmax[ni]));
    __syncthreads();
    atomicMax((unsigned int*)&pmax[tid], __float_as_uint(smax[tid]));
}

// ---------------- node GEMM (A from bf16 xb) ----------------
__global__ __launch_bounds__(256, 3) void node_gemm_kernel(
    const unsigned short* __restrict__ xb,
    const unsigned short* __restrict__ Wpt,
    unsigned short* __restrict__ yp)
{
    __shared__ unsigned short sA[2][64][40];
    __shared__ unsigned short sB[2][256][32];

    const int tid = threadIdx.x, lane = tid & 63, wid = tid >> 6;
    const int wm = wid >> 1, wn = wid & 1, l15 = lane & 15, l4 = lane >> 4;
    const int node0 = blockIdx.x * 64;
    const int n0 = blockIdx.y * 256;
    const int arow = tid >> 2, s3 = tid & 3;

    int nodeA = node0 + arow; if (nodeA >= NC) nodeA = NC - 1;

    f32x4 acc[2][8];
    #pragma unroll
    for (int mi = 0; mi < 2; ++mi)
        #pragma unroll
        for (int ni = 0; ni < 8; ++ni)
            acc[mi][ni] = (f32x4){0.f, 0.f, 0.f, 0.f};

    #pragma unroll
    for (int i = 0; i < 4; ++i) {
        int n = (wid << 6) + (i << 4) + (lane >> 2);
        gload_lds16(Wpt + (size_t)(n0 + n) * 256 + (lane & 3) * 8, &sB[0][(wid << 6) + (i << 4)][0]);
    }
    *(int4*)&sA[0][arow][s3 * 8] = *(const int4*)(xb + (size_t)nodeA * 256 + s3 * 8);
    __syncthreads();

    int buf = 0;
    for (int ch = 0; ch < 8; ++ch) {
        const int nch = ch + 1;
        int4 areg;
        if (nch < 8) {
            #pragma unroll
            for (int i = 0; i < 4; ++i) {
                int n = (wid << 6) + (i << 4) + (lane >> 2);
                gload_lds16(Wpt + (size_t)(n0 + n) * 256 + nch * 32 + (lane & 3) * 8,
                            &sB[buf ^ 1][(wid << 6) + (i << 4)][0]);
            }
            areg = *(const int4*)(xb + (size_t)nodeA * 256 + nch * 32 + s3 * 8);
        }
        bf16x8 af[2];
        #pragma unroll
        for (int mi = 0; mi < 2; ++mi)
            af[mi] = *(const bf16x8*)&sA[buf][wm * 32 + mi * 16 + l15][l4 * 8];
        #pragma unroll
        for (int ni = 0; ni < 8; ++ni) {
            int n = wn * 128 + ni * 16 + l15;
            bf16x8 bfr = *(const bf16x8*)&sB[buf][n][(l4 ^ (n & 3)) * 8];
            acc[0][ni] = __builtin_amdgcn_mfma_f32_16x16x32_bf16(af[0], bfr, acc[0][ni], 0, 0, 0);
            acc[1][ni] = __builtin_amdgcn_mfma_f32_16x16x32_bf16(af[1], bfr, acc[1][ni], 0, 0, 0);
        }
        if (nch < 8) *(int4*)&sA[buf ^ 1][arow][s3 * 8] = areg;
        __syncthreads();
        buf ^= 1;
    }

    #pragma unroll
    for (int mi = 0; mi < 2; ++mi) {
        #pragma unroll
        for (int r = 0; r < 4; ++r) {
            int node = node0 + wm * 32 + mi * 16 + l4 * 4 + r;
            if (node < NC) {
                #pragma unroll
                for (int ni = 0; ni < 8; ++ni)
                    yp[(size_t)node * 512 + n0 + wn * 128 + ni * 16 + l15] = f2bf(acc[mi][ni][r]);
            }
        }
    }
}

// ---------------- node GEMM, A = bf16(accb * inv); also folds iter-0 pmax ----------------
__global__ __launch_bounds__(256, 3) void node_gemm_scaled_kernel(
    const float* __restrict__ accb, const float* __restrict__ invv,
    const unsigned short* __restrict__ Wpt,
    unsigned short* __restrict__ yp, float* __restrict__ pmax0)
{
    __shared__ unsigned short sA[2][64][40];
    __shared__ unsigned short sB[2][256][32];
    __shared__ float smax[256];

    const int tid = threadIdx.x, lane = tid & 63, wid = tid >> 6;
    const int wm = wid >> 1, wn = wid & 1, l15 = lane & 15, l4 = lane >> 4;
    const int node0 = blockIdx.x * 64;
    const int n0 = blockIdx.y * 256;
    const int arow = tid >> 2, s3 = tid & 3;

    smax[tid] = 0.0f;

    int nodeA = node0 + arow; if (nodeA >= NC) nodeA = NC - 1;
    const float inv_n = invv[nodeA];

    f32x4 acc[2][8];
    #pragma unroll
    for (int mi = 0; mi < 2; ++mi)
        #pragma unroll
        for (int ni = 0; ni < 8; ++ni)
            acc[mi][ni] = (f32x4){0.f, 0.f, 0.f, 0.f};

    #pragma unroll
    for (int i = 0; i < 4; ++i) {
        int n = (wid << 6) + (i << 4) + (lane >> 2);
        gload_lds16(Wpt + (size_t)(n0 + n) * 256 + (lane & 3) * 8, &sB[0][(wid << 6) + (i << 4)][0]);
    }
    {
        float4 a0 = *(const float4*)(accb + (size_t)nodeA * 256 + s3 * 8);
        float4 a1 = *(const float4*)(accb + (size_t)nodeA * 256 + s3 * 8 + 4);
        float v0=a0.x*inv_n, v1=a0.y*inv_n, v2=a0.z*inv_n, v3=a0.w*inv_n;
        float v4=a1.x*inv_n, v5=a1.y*inv_n, v6=a1.z*inv_n, v7=a1.w*inv_n;
        union { unsigned short u[8]; int4 v; } pk;
        pk.u[0]=f2bf(v0); pk.u[1]=f2bf(v1); pk.u[2]=f2bf(v2); pk.u[3]=f2bf(v3);
        pk.u[4]=f2bf(v4); pk.u[5]=f2bf(v5); pk.u[6]=f2bf(v6); pk.u[7]=f2bf(v7);
        *(int4*)&sA[0][arow][s3 * 8] = pk.v;
        int c0 = s3 * 8;
        atomicMax((unsigned int*)&smax[c0+0], __float_as_uint(v0));
        atomicMax((unsigned int*)&smax[c0+1], __float_as_uint(v1));
        atomicMax((unsigned int*)&smax[c0+2], __float_as_uint(v2));
        atomicMax((unsigned int*)&smax[c0+3], __float_as_uint(v3));
        atomicMax((unsigned int*)&smax[c0+4], __float_as_uint(v4));
        atomicMax((unsigned int*)&smax[c0+5], __float_as_uint(v5));
        atomicMax((unsigned int*)&smax[c0+6], __float_as_uint(v6));
        atomicMax((unsigned int*)&smax[c0+7], __float_as_uint(v7));
    }
    __syncthreads();

    int buf = 0;
    for (int ch = 0; ch < 8; ++ch) {
        const int nch = ch + 1;
        float4 f4a, f4b;
        if (nch < 8) {
            #pragma unroll
            for (int i = 0; i < 4; ++i) {
                int n = (wid << 6) + (i << 4) + (lane >> 2);
                gload_lds16(Wpt + (size_t)(n0 + n) * 256 + nch * 32 + (lane & 3) * 8,
                            &sB[buf ^ 1][(wid << 6) + (i << 4)][0]);
            }
            f4a = *(const float4*)(accb + (size_t)nodeA * 256 + nch * 32 + s3 * 8);
            f4b = *(const float4*)(accb + (size_t)nodeA * 256 + nch * 32 + s3 * 8 + 4);
        }
        bf16x8 af[2];
        #pragma unroll
        for (int mi = 0; mi < 2; ++mi)
            af[mi] = *(const bf16x8*)&sA[buf][wm * 32 + mi * 16 + l15][l4 * 8];
        #pragma unroll
        for (int ni = 0; ni < 8; ++ni) {
            int n = wn * 128 + ni * 16 + l15;
            bf16x8 bfr = *(const bf16x8*)&sB[buf][n][(l4 ^ (n & 3)) * 8];
            acc[0][ni] = __builtin_amdgcn_mfma_f32_16x16x32_bf16(af[0], bfr, acc[0][ni], 0, 0, 0);
            acc[1][ni] = __builtin_amdgcn_mfma_f32_16x16x32_bf16(af[1], bfr, acc[1][ni], 0, 0, 0);
        }
        if (nch < 8) {
            float v0=f4a.x*inv_n, v1=f4a.y*inv_n, v2=f4a.z*inv_n, v3=f4a.w*inv_n;
            float v4=f4b.x*inv_n, v5=f4b.y*inv_n, v6=f4b.z*inv_n, v7=f4b.w*inv_n;
            union { unsigned short u[8]; int4 v; } pk;
            pk.u[0]=f2bf(v0); pk.u[1]=f2bf(v1); pk.u[2]=f2bf(v2); pk.u[3]=f2bf(v3);
            pk.u[4]=f2bf(v4); pk.u[5]=f2bf(v5); pk.u[6]=f2bf(v6); pk.u[7]=f2bf(v7);
            *(int4*)&sA[buf ^ 1][arow][s3 * 8] = pk.v;
            int c0 = nch * 32 + s3 * 8;
            atomicMax((unsigned int*)&smax[c0+0], __float_as_uint(v0));
            atomicMax((unsigned int*)&smax[c0+1], __float_as_uint(v1));
            atomicMax((unsigned int*)&smax[c0+2], __float_as_uint(v2));
            atomicMax((unsigned int*)&smax[c0+3], __float_as_uint(v3));
            atomicMax((unsigned int*)&smax[c0+4], __float_as_uint(v4));
            atomicMax((unsigned int*)&smax[c0+5], __float_as_uint(v5));
            atomicMax((unsigned int*)&smax[c0+6], __float_as_uint(v6));
            atomicMax((unsigned int*)&smax[c0+7], __float_as_uint(v7));
        }
        __syncthreads();
        buf ^= 1;
    }

    #pragma unroll
    for (int mi = 0; mi < 2; ++mi) {
        #pragma unroll
        for (int r = 0; r < 4; ++r) {
            int node = node0 + wm * 32 + mi * 16 + l4 * 4 + r;
            if (node < NC) {
                #pragma unroll
                for (int ni = 0; ni < 8; ++ni)
                    yp[(size_t)node * 512 + n0 + wn * 128 + ni * 16 + l15] = f2bf(acc[mi][ni][r]);
            }
        }
    }
    atomicMax((unsigned int*)&pmax0[tid], __float_as_uint(smax[tid]));
}

// ---------------- counting sort of edges by src ----------------
__global__ __launch_bounds__(256) void count_int_kernel(
    const int* __restrict__ eidx, int* __restrict__ icnt)
{
    int t = blockIdx.x * 256 + threadIdx.x;
    if (t < NE) atomicAdd(&icnt[eidx[2 * t]], 1);
}

__global__ __launch_bounds__(256) void scan1_kernel(
    const int* __restrict__ icnt, int* __restrict__ part)
{
    __shared__ int sd[256];
    int i = blockIdx.x * 256 + threadIdx.x;
    sd[threadIdx.x] = (i < NC) ? icnt[i] : 0;
    __syncthreads();
    for (int d = 128; d > 0; d >>= 1) {
        if (threadIdx.x < d) sd[threadIdx.x] += sd[threadIdx.x + d];
        __syncthreads();
    }
    if (threadIdx.x == 0) part[blockIdx.x] = sd[0];
}

__global__ void scan2_kernel(int* __restrict__ part)
{
    if (threadIdx.x == 0) {
        int acc = 0;
        for (int i = 0; i < NB_SCAN; ++i) { int v = part[i]; part[i] = acc; acc += v; }
    }
}

__global__ __launch_bounds__(256) void scan3_kernel(
    const int* __restrict__ icnt, const int* __restrict__ part,
    int* __restrict__ cur)
{
    __shared__ int sc[256];
    const int t = threadIdx.x;
    int i = blockIdx.x * 256 + t;
    int val = (i < NC) ? icnt[i] : 0;
    sc[t] = val;
    __syncthreads();
    for (int d = 1; d < 256; d <<= 1) {
        int x = (t >= d) ? sc[t - d] : 0;
        __syncthreads();
        sc[t] += x;
        __syncthreads();
    }
    if (i < NC) cur[i] = part[blockIdx.x] + sc[t] - val;
}

__global__ __launch_bounds__(256) void bin_kernel(
    const int* __restrict__ eidx, int* __restrict__ cur, int* __restrict__ perm)
{
    int t = blockIdx.x * 256 + threadIdx.x;
    if (t < NE) {
        int s = eidx[2 * t];
        int p = atomicAdd(&cur[s], 1);
        perm[p] = t;
    }
}

__global__ __launch_bounds__(256) void inv_kernel(
    const int* __restrict__ icnt, float* __restrict__ inv)
{
    int t = blockIdx.x * 256 + threadIdx.x;
    if (t < NC) inv[t] = 1.0f / fmaxf((float)icnt[t], 1.0f);
}

// ---------------- ef prep: bf16, sorted edge order, chunk-major; pre-permuted src/dst ----
__global__ __launch_bounds__(256) void ef_prep_kernel(
    const float* __restrict__ eto, const float* __restrict__ efe,
    const int* __restrict__ perm, const int* __restrict__ eidx,
    unsigned short* __restrict__ efc01, unsigned short* __restrict__ efc2,
    int* __restrict__ esrc, int* __restrict__ edst)
{
    int p = blockIdx.x * 256 + threadIdx.x;
    if (p >= NE) return;
    int e = perm[p];
    esrc[p] = eidx[2 * e];
    edst[p] = eidx[2 * e + 1];
    const float* efr = efe + (size_t)e * 64;

    union { unsigned short u[8]; int4 v; } pk;
    {
        float4 a = *(const float4*)(eto + (size_t)e * 4);
        float4 b = *(const float4*)(efr + 0);
        pk.u[0]=f2bf(a.x); pk.u[1]=f2bf(a.y); pk.u[2]=f2bf(a.z); pk.u[3]=f2bf(a.w);
        pk.u[4]=f2bf(b.x); pk.u[5]=f2bf(b.y); pk.u[6]=f2bf(b.z); pk.u[7]=f2bf(b.w);
        *(int4*)(efc01 + (size_t)p * 32) = pk.v;
    }
    #pragma unroll
    for (int g = 1; g < 4; ++g) {
        float4 a = *(const float4*)(efr + g * 8 - 4);
        float4 b = *(const float4*)(efr + g * 8);
        pk.u[0]=f2bf(a.x); pk.u[1]=f2bf(a.y); pk.u[2]=f2bf(a.z); pk.u[3]=f2bf(a.w);
        pk.u[4]=f2bf(b.x); pk.u[5]=f2bf(b.y); pk.u[6]=f2bf(b.z); pk.u[7]=f2bf(b.w);
        *(int4*)(efc01 + (size_t)p * 32 + g * 8) = pk.v;
    }
    #pragma unroll
    for (int g = 0; g < 4; ++g) {
        float4 a = *(const float4*)(efr + 28 + g * 8);
        float4 b = *(const float4*)(efr + 32 + g * 8);
        pk.u[0]=f2bf(a.x); pk.u[1]=f2bf(a.y); pk.u[2]=f2bf(a.z); pk.u[3]=f2bf(a.w);
        pk.u[4]=f2bf(b.x); pk.u[5]=f2bf(b.y); pk.u[6]=f2bf(b.z); pk.u[7]=f2bf(b.w);
        *(int4*)(efc01 + ((size_t)NEP + p) * 32 + g * 8) = pk.v;
    }
    {
        float4 a = *(const float4*)(efr + 60);
        pk.u[0]=f2bf(a.x); pk.u[1]=f2bf(a.y); pk.u[2]=f2bf(a.z); pk.u[3]=f2bf(a.w);
        pk.u[4]=0; pk.u[5]=0; pk.u[6]=0; pk.u[7]=0;
        *(int4*)(efc2 + (size_t)p * 8) = pk.v;
    }
}

// gather + walk macros (independent loads, no cross-row state; rule #20 safe)
#define LOAD16(B, YT, YM)                                              \
    _Pragma("unroll")                                                  \
    for (int r = 0; r < 16; ++r) {                                     \
        int row = (B) * 16 + r;                                        \
        YT[r] = bf2f(yp[((unsigned)s_src[row] << 9) + (unsigned)col]); \
        YM[r] = bf2f(yp[((unsigned)s_dst[row] << 9) + 256u + (unsigned)col]); \
    }

#define WALK16(B, YT, YM)                                              \
    _Pragma("unroll")                                                  \
    for (int r = 0; r < 16; ++r) {                                     \
        int row = (B) * 16 + r;                                        \
        float v = 0.0f;                                                \
        if (e0 + row < NE)                                             \
            v = fmaxf(bf2f(epb[row][col]) + YT[r] + YM[r] + b_col, 0.f); \
        int sr = s_src[row];                                           \
        if (sr != curn) {                                              \
            if (rstart > 0) accb[(size_t)curn * 256 + col] = run;      \
            else            atomicAdd(&accb[(size_t)curn * 256 + col], run); \
            curn = sr; run = v; rstart = row;                          \
        } else {                                                       \
            run += v;                                                  \
        }                                                              \
    }

// ---------------- combine (efc path): single-sW MFMA + one-shot bf16 ep staging +
//                  barrier-free 64-row walk with depth-2 pipelined gathers ----------------
__global__ __launch_bounds__(256, 4) void combine_efc_kernel(
    const unsigned short* __restrict__ yp,
    const unsigned short* __restrict__ efc01,
    const unsigned short* __restrict__ efc2,
    const int* __restrict__ esrc, const int* __restrict__ edst,
    const unsigned short* __restrict__ Wbt,
    const float* __restrict__ bias,
    float* __restrict__ accb)
{
    __shared__ __align__(16) unsigned char smem[34816];
    unsigned short (*sA01)[64][32] = (unsigned short (*)[64][32])(smem);
    unsigned short (*sA2)[8]       = (unsigned short (*)[8])(smem + 8192);
    unsigned short (*sW)[32]       = (unsigned short (*)[32])(smem + 9216);
    unsigned short (*epb)[272]     = (unsigned short (*)[272])(smem);
    __shared__ int s_src[64], s_dst[64];

    const int tid = threadIdx.x;
    const int nwg = gridDim.x;
    const int q = nwg >> 3, rr = nwg & 7;
    const int xcd = blockIdx.x & 7, within = blockIdx.x >> 3;
    const int bid = (xcd < rr ? xcd * (q + 1) : rr * (q + 1) + (xcd - rr) * q) + within;
    const int e0 = bid * 64;

    const int lane = tid & 63;
    const int wid  = tid >> 6;
    const int wm   = wid >> 1;
    const int wn   = wid & 1;
    const int l15  = lane & 15;
    const int l4   = lane >> 4;

    if (tid < 64) {
        int e = e0 + tid; if (e > NE - 1) e = NE - 1;
        s_src[tid] = esrc[e];
        s_dst[tid] = edst[e];
    }
    gload_lds16(efc01 + ((size_t)e0 + wid * 16) * 32 + lane * 8, &sA01[0][wid * 16][0]);
    gload_lds16(efc01 + ((size_t)NEP + e0 + wid * 16) * 32 + lane * 8, &sA01[1][wid * 16][0]);
    if (wid == 0)
        gload_lds16(efc2 + (size_t)e0 * 8 + lane * 8, &sA2[0][0]);
    #pragma unroll
    for (int i = 0; i < 4; ++i) {
        gload_lds16(Wbt + (size_t)((wid << 6) + (i << 4) + (lane >> 2)) * KB + (lane & 3) * 8,
                    &sW[(wid << 6) + (i << 4)][0]);
    }
    __syncthreads();

    f32x4 acc[2][8];
    #pragma unroll
    for (int mi = 0; mi < 2; ++mi)
        #pragma unroll
        for (int ni = 0; ni < 8; ++ni)
            acc[mi][ni] = (f32x4){0.f, 0.f, 0.f, 0.f};

    #pragma unroll
    for (int ch = 0; ch < 3; ++ch) {
        if (ch > 0) {
            __syncthreads();
            #pragma unroll
            for (int i = 0; i < 4; ++i) {
                gload_lds16(Wbt + (size_t)((wid << 6) + (i << 4) + (lane >> 2)) * KB + ch * 32 + (lane & 3) * 8,
                            &sW[(wid << 6) + (i << 4)][0]);
            }
            __syncthreads();
        }
        bf16x8 af0, af1;
        if (ch < 2) {
            af0 = *(const bf16x8*)&sA01[ch][wm * 32 + l15][l4 * 8];
            af1 = *(const bf16x8*)&sA01[ch][wm * 32 + 16 + l15][l4 * 8];
        } else {
            bf16x8 z = (bf16x8){0,0,0,0,0,0,0,0};
            bf16x8 a0 = *(const bf16x8*)&sA2[wm * 32 + l15][0];
            bf16x8 a1 = *(const bf16x8*)&sA2[wm * 32 + 16 + l15][0];
            af0 = (l4 == 0) ? a0 : z;
            af1 = (l4 == 0) ? a1 : z;
        }
        #pragma unroll
        for (int ni = 0; ni < 8; ++ni) {
            int n = wn * 128 + ni * 16 + l15;
            bf16x8 bfr = *(const bf16x8*)&sW[n][(l4 ^ (n & 3)) * 8];
            acc[0][ni] = __builtin_amdgcn_mfma_f32_16x16x32_bf16(af0, bfr, acc[0][ni], 0, 0, 0);
            acc[1][ni] = __builtin_amdgcn_mfma_f32_16x16x32_bf16(af1, bfr, acc[1][ni], 0, 0, 0);
        }
    }
    __syncthreads();

    // one-shot staging: whole 64x256 tile to bf16 LDS; acc dies here
    #pragma unroll
    for (int mi = 0; mi < 2; ++mi)
        #pragma unroll
        for (int ni = 0; ni < 8; ++ni)
            #pragma unroll
            for (int r = 0; r < 4; ++r)
                epb[wm * 32 + mi * 16 + l4 * 4 + r][wn * 128 + ni * 16 + l15] = f2bf(acc[mi][ni][r]);

    const int col = tid;
    const float b_col = bias[col];
    float ytA[16], ymA[16], ytB[16], ymB[16];
    LOAD16(0, ytA, ymA)
    LOAD16(1, ytB, ymB)
    __syncthreads();   // epb visible

    int curn = s_src[0];
    int rstart = 0;
    float run = 0.f;

    WALK16(0, ytA, ymA)
    LOAD16(2, ytA, ymA)
    WALK16(1, ytB, ymB)
    LOAD16(3, ytB, ymB)
    WALK16(2, ytA, ymA)
    WALK16(3, ytB, ymB)

    atomicAdd(&accb[(size_t)curn * 256 + col], run);
}

// ---------------- combine (fallback, R8-exact): fp32 ef staging via perm ----------------
__global__ __launch_bounds__(256, 3) void combine_f32_kernel(
    const unsigned short* __restrict__ yp,
    const float* __restrict__ eto, const float* __restrict__ efe,
    const int* __restrict__ eidx, const int* __restrict__ perm,
    const unsigned short* __restrict__ Wbt,
    const float* __restrict__ bias,
    float* __restrict__ accb)
{
    __shared__ unsigned short sA[3][64][40];
    __shared__ unsigned short sW[2][256][32];
    __shared__ int s_src[64], s_dst[64], s_perm[64];

    const int tid = threadIdx.x;
    const int nwg = gridDim.x;
    const int q = nwg >> 3, rr = nwg & 7;
    const int xcd = blockIdx.x & 7, within = blockIdx.x >> 3;
    const int bid = (xcd < rr ? xcd * (q + 1) : rr * (q + 1) + (xcd - rr) * q) + within;
    const int e0 = bid * 64;

    if (tid < 64) {
        int ee = e0 + tid; if (ee >= NE) ee = NE - 1;
        int e = perm[ee];
        s_perm[tid] = e;
        s_src[tid] = eidx[2 * e];
        s_dst[tid] = eidx[2 * e + 1];
    }
    const int lane = tid & 63;
    const int wid  = tid >> 6;
    const int wm   = wid >> 1;
    const int wn   = wid & 1;
    const int l15  = lane & 15;
    const int l4   = lane >> 4;
    const int arow = tid >> 2;
    const int s3   = tid & 3;

    f32x4 acc[2][8];
    #pragma unroll
    for (int mi = 0; mi < 2; ++mi)
        #pragma unroll
        for (int ni = 0; ni < 8; ++ni)
            acc[mi][ni] = (f32x4){0.f, 0.f, 0.f, 0.f};

    #pragma unroll
    for (int i = 0; i < 4; ++i) {
        int n = (wid << 6) + (i << 4) + (lane >> 2);
        gload_lds16(Wbt + (size_t)n * KB + (lane & 3) * 8, &sW[0][(wid << 6) + (i << 4)][0]);
    }
    __syncthreads();

    const int my_e = s_perm[arow];
    #pragma unroll
    for (int ch = 0; ch < 3; ++ch) {
        int g0 = ch * 32 + s3 * 8;
        union { unsigned short u[8]; int4 v; } pk;
        #pragma unroll
        for (int j = 0; j < 8; ++j) {
            int g = g0 + j;
            float f = 0.0f;
            if (g < 4)       f = eto[(size_t)my_e * 4 + g];
            else if (g < 68) f = efe[(size_t)my_e * 64 + (g - 4)];
            pk.u[j] = f2bf(f);
        }
        *(int4*)&sA[ch][arow][s3 * 8] = pk.v;
    }
    __syncthreads();

    int buf = 0;
    #pragma unroll
    for (int ch = 0; ch < 3; ++ch) {
        if (ch + 1 < 3) {
            #pragma unroll
            for (int i = 0; i < 4; ++i) {
                int n = (wid << 6) + (i << 4) + (lane >> 2);
                gload_lds16(Wbt + (size_t)n * KB + (ch + 1) * 32 + (lane & 3) * 8,
                            &sW[buf ^ 1][(wid << 6) + (i << 4)][0]);
            }
        }
        bf16x8 af[2];
        #pragma unroll
        for (int mi = 0; mi < 2; ++mi)
            af[mi] = *(const bf16x8*)&sA[ch][wm * 32 + mi * 16 + l15][l4 * 8];
        #pragma unroll
        for (int ni = 0; ni < 8; ++ni) {
            int n = wn * 128 + ni * 16 + l15;
            bf16x8 bfr = *(const bf16x8*)&sW[buf][n][(l4 ^ (n & 3)) * 8];
            acc[0][ni] = __builtin_amdgcn_mfma_f32_16x16x32_bf16(af[0], bfr, acc[0][ni], 0, 0, 0);
            acc[1][ni] = __builtin_amdgcn_mfma_f32_16x16x32_bf16(af[1], bfr, acc[1][ni], 0, 0, 0);
        }
        __syncthreads();
        buf ^= 1;
    }

    float (*ep)[258] = (float (*)[258])(&sW[0][0][0]);
    const int col = tid;
    const float b_col = bias[col];

    int curn = s_src[0];
    int rstart = 0;
    float run = 0.f;
    #pragma unroll
    for (int c = 0; c < 4; ++c) {
        if (wm == (c >> 1)) {
            const int mi = c & 1;
            #pragma unroll
            for (int ni = 0; ni < 8; ++ni) {
                #pragma unroll
                for (int r = 0; r < 4; ++r)
                    ep[l4 * 4 + r][wn * 128 + ni * 16 + l15] = acc[mi][ni][r];
            }
        }
        float yt[16], ym[16];
        #pragma unroll
        for (int r = 0; r < 16; ++r) {
            int row = c * 16 + r;
            yt[r] = bf2f(yp[(size_t)s_src[row] * 512 + col]);
            ym[r] = bf2f(yp[(size_t)s_dst[row] * 512 + 256 + col]);
        }
        __syncthreads();
        #pragma unroll
        for (int r = 0; r < 16; ++r) {
            int row = c * 16 + r;
            float v = 0.0f;
            if (e0 + row < NE)
                v = fmaxf(ep[r][col] + yt[r] + ym[r] + b_col, 0.f);
            int sr = s_src[row];
            if (sr != curn) {
                if (rstart > 0) accb[(size_t)curn * 256 + col] = run;
                else            atomicAdd(&accb[(size_t)curn * 256 + col], run);
                curn = sr; run = v; rstart = row;
            } else {
                run += v;
            }
        }
        __syncthreads();
    }
    atomicAdd(&accb[(size_t)curn * 256 + col], run);
}

// ---------------- per-node scale + bf16 convert + column max (fallback path) ----------------
__global__ __launch_bounds__(256) void finalize_kernel(
    const float* __restrict__ src, const float* __restrict__ inv,
    unsigned short* __restrict__ xb_out, float* __restrict__ pmax, int n)
{
    const int tid = threadIdx.x;
    int i0 = blockIdx.x * 128;
    int iend = i0 + 128; if (iend > n) iend = n;
    float m = 0.0f;
    for (int i = i0; i < iend; ++i) {
        float v = src[(size_t)i * 256 + tid];
        v *= inv[i];
        xb_out[(size_t)i * 256 + tid] = f2bf(v);
        m = fmaxf(m, v);
    }
    atomicMax((unsigned int*)&pmax[tid], __float_as_uint(m));
}

// ---------------- pmax-only pass (efc path, final layer) ----------------
__global__ __launch_bounds__(256) void pmax_only_kernel(
    const float* __restrict__ src, const float* __restrict__ inv,
    float* __restrict__ pmax, int n)
{
    const int tid = threadIdx.x;
    int i0 = blockIdx.x * 128;
    int iend = i0 + 128; if (iend > n) iend = n;
    float m = 0.0f;
    for (int i = i0; i < iend; ++i)
        m = fmaxf(m, src[(size_t)i * 256 + tid] * inv[i]);
    atomicMax((unsigned int*)&pmax[tid], __float_as_uint(m));
}

__global__ __launch_bounds__(256) void parent_kernel(
    const float* __restrict__ pmax, const float* __restrict__ W,
    const float* __restrict__ bias, float* __restrict__ out)
{
    __shared__ float sp[768];
    const int tid = threadIdx.x;
    for (int i = tid; i < 768; i += 256) sp[i] = pmax[i];
    __syncthreads();
    float s = bias[tid];
    for (int k = 0; k < 768; ++k) s = fmaf(sp[k], W[(size_t)k * 256 + tid], s);
    out[tid] = fmaxf(s, 0.f);
}

extern "C" void kernel_launch(void* const* d_in, const int* in_sizes, int n_in,
                              void* d_out, int out_size, void* d_ws, size_t ws_size,
                              hipStream_t stream)
{
    const float* cf   = (const float*)d_in[0];
    const float* ex   = (const float*)d_in[1];
    const float* eto  = (const float*)d_in[2];
    const float* efe  = (const float*)d_in[3];
    const int*   eidx = (const int*)d_in[4];
    const float* Wc   = (const float*)d_in[5];
    const float* bc   = (const float*)d_in[6];
    const float* W0   = (const float*)d_in[7];
    const float* b0   = (const float*)d_in[8];
    const float* W1   = (const float*)d_in[9];
    const float* b1   = (const float*)d_in[10];
    const float* Wp   = (const float*)d_in[11];
    const float* bp   = (const float*)d_in[12];

    float*          accb = (float*)d_ws;                          // NC*256 f32
    float*          invv = accb + (size_t)NC * 256;               // NC
    float*          pmax = invv + NC;                             // 768
    unsigned short* xb   = (unsigned short*)(pmax + 768);         // NC*256
    unsigned short* yp   = xb + (size_t)NC * 256;                 // NC*512
    unsigned short* Wpt  = yp + (size_t)NC * 512;                 // 2*512*256
    unsigned short* Wbt  = Wpt + (size_t)2 * 512 * 256;           // 2*256*KB
    unsigned short* Wct  = Wbt + (size_t)2 * 256 * KB;            // 256*KPC
    int*            icnt = (int*)(Wct + (size_t)256 * KPC);       // NC
    int*            part = icnt + NC;                             // 256
    int*            curb = part + 256;                            // NC
    int*            perm = curb + NC;                             // NE
    unsigned short* efc01 = (unsigned short*)(perm + NE);         // 2*NEP*32
    unsigned short* efc2  = efc01 + (size_t)2 * NEP * 32;         // NEP*8
    int*            esrc  = (int*)(efc2 + (size_t)NEP * 8);       // NE
    int*            edst  = esrc + NE;                            // NE
    size_t need = (size_t)((char*)(edst + NE) - (char*)d_ws);
    const bool use_efc = (ws_size >= need);

    hipMemsetAsync(pmax, 0, 768 * sizeof(float), stream);
    hipMemsetAsync(icnt, 0, NC * sizeof(int), stream);

    prep_w_kernel<<<1792, 256, 0, stream>>>(W0, W1, Wc, Wpt, Wbt, Wct);
    child_mfma_kernel<<<(NC + 63) / 64, 256, 0, stream>>>(cf, ex, Wct, bc, xb, pmax);

    count_int_kernel<<<(NE + 255) / 256, 256, 0, stream>>>(eidx, icnt);
    scan1_kernel<<<NB_SCAN, 256, 0, stream>>>(icnt, part);
    scan2_kernel<<<1, 64, 0, stream>>>(part);
    scan3_kernel<<<NB_SCAN, 256, 0, stream>>>(icnt, part, curb);
    bin_kernel<<<(NE + 255) / 256, 256, 0, stream>>>(eidx, curb, perm);
    inv_kernel<<<(NC + 255) / 256, 256, 0, stream>>>(icnt, invv);
    if (use_efc)
        ef_prep_kernel<<<(NE + 255) / 256, 256, 0, stream>>>(eto, efe, perm, eidx, efc01, efc2, esrc, edst);

    const int nwg = (NE + 63) / 64;
    if (use_efc) {
        // iter 0
        node_gemm_kernel<<<dim3((NC + 63) / 64, 2), 256, 0, stream>>>(xb, Wpt, yp);
        hipMemsetAsync(accb, 0, (size_t)NC * 256 * sizeof(float), stream);
        combine_efc_kernel<<<nwg, 256, 0, stream>>>(
            yp, efc01, efc2, esrc, edst, Wbt, b0, accb);
        // iter 1: A staged from accb*inv (no xb round-trip); iter-0 pmax folded in
        node_gemm_scaled_kernel<<<dim3((NC + 63) / 64, 2), 256, 0, stream>>>(
            accb, invv, Wpt + (size_t)512 * 256, yp, pmax + 256);
        hipMemsetAsync(accb, 0, (size_t)NC * 256 * sizeof(float), stream);
        combine_efc_kernel<<<nwg, 256, 0, stream>>>(
            yp, efc01, efc2, esrc, edst, Wbt + (size_t)256 * KB, b1, accb);
        pmax_only_kernel<<<(NC + 127) / 128, 256, 0, stream>>>(accb, invv, pmax + 512, NC);
    } else {
        for (int it = 0; it < 2; ++it) {
            node_gemm_kernel<<<dim3((NC + 63) / 64, 2), 256, 0, stream>>>(
                xb, Wpt + (size_t)it * 512 * 256, yp);
            hipMemsetAsync(accb, 0, (size_t)NC * 256 * sizeof(float), stream);
            combine_f32_kernel<<<nwg, 256, 0, stream>>>(
                yp, eto, efe, eidx, perm,
                Wbt + (size_t)it * 256 * KB, it ? b1 : b0, accb);
            finalize_kernel<<<(NC + 127) / 128, 256, 0, stream>>>(accb, invv, xb, pmax + 256 * (it + 1), NC);
        }
    }
    parent_kernel<<<1, 256, 0, stream>>>(pmax, Wp, bp, (float*)d_out);
}